// Round 1
// baseline (894.675 us; speedup 1.0000x reference)
//
#include <hip/hip_runtime.h>
#include <math.h>
#include <stdint.h>

typedef _Float16 half8 __attribute__((ext_vector_type(8)));
typedef _Float16 half2v __attribute__((ext_vector_type(2)));
typedef float    f32x4 __attribute__((ext_vector_type(4)));
typedef unsigned int uint4v __attribute__((ext_vector_type(4)));

constexpr int Bc = 16, Nn = 2048, Dd = 256;
constexpr int QTI = 64;   // q rows per block (4 waves x 16)
constexpr int MC  = 64;   // m-chunk per iteration

__device__ _Float16 g_Wt[Dd * Dd];   // W^T, f16  (o-major: g_Wt[o][i])

// ---------- transpose W (fp32 [i][o]) -> g_Wt (f16 [o][i]) ----------
__global__ void __launch_bounds__(256)
wt_transpose_kernel(const float* __restrict__ W) {
    __shared__ float ts[64][65];
    const int t = threadIdx.x;
    const int r0 = blockIdx.x * 64;   // i tile
    const int c0 = blockIdx.y * 64;   // o tile
    for (int idx = t; idx < 64 * 64; idx += 256) {
        const int i = idx >> 6, j = idx & 63;
        ts[i][j] = W[(r0 + i) * Dd + c0 + j];
    }
    __syncthreads();
    for (int idx = t; idx < 64 * 64; idx += 256) {
        const int c = idx >> 6, rl = idx & 63;
        g_Wt[(c0 + c) * Dd + r0 + rl] = (_Float16)ts[rl][c];
    }
}

// ---------- fused: h = nodes @ W (MFMA) + emit vt = nodes^T (f16) ----------
// 512 blocks x 256 thr; wave owns 16 rows. Transpose is per-wave LDS (no
// __syncthreads): wave's 16 n-rows x 64 d-chunk staged, read back d-major.
__global__ void __launch_bounds__(256, 2)
hgemm_vt_kernel(const float* __restrict__ nodes, _Float16* __restrict__ h16,
                _Float16* __restrict__ vt) {
    __shared__ float ts[4][16][68];
    const int t = threadIdx.x, w = t >> 6, lane = t & 63;
    const int quad = lane >> 4, l16 = lane & 15;
    const size_t row0 = (size_t)blockIdx.x * 64 + 16 * w;

    // ---- h = nodes @ W ----
    half8 aq[8];
    {
        const float* src = nodes + (row0 + l16) * Dd + quad * 8;
        #pragma unroll
        for (int kf = 0; kf < 8; ++kf) {
            const f32x4 a0 = *(const f32x4*)(src + kf * 32);
            const f32x4 a1 = *(const f32x4*)(src + kf * 32 + 4);
            half8 a;
            a[0] = (_Float16)a0[0]; a[1] = (_Float16)a0[1];
            a[2] = (_Float16)a0[2]; a[3] = (_Float16)a0[3];
            a[4] = (_Float16)a1[0]; a[5] = (_Float16)a1[1];
            a[6] = (_Float16)a1[2]; a[7] = (_Float16)a1[3];
            aq[kf] = a;
        }
    }
    f32x4 acc[16];
    #pragma unroll
    for (int ot = 0; ot < 16; ++ot) acc[ot] = (f32x4){0.f, 0.f, 0.f, 0.f};
    #pragma unroll
    for (int kf = 0; kf < 8; ++kf) {
        #pragma unroll
        for (int ot = 0; ot < 16; ++ot) {
            const half8 bw = *(const half8*)&g_Wt[(ot * 16 + l16) * Dd + kf * 32 + quad * 8];
            acc[ot] = __builtin_amdgcn_mfma_f32_16x16x32_f16(aq[kf], bw, acc[ot], 0, 0, 0);
        }
    }
    #pragma unroll
    for (int ot = 0; ot < 16; ++ot)
        #pragma unroll
        for (int r = 0; r < 4; ++r)
            h16[(row0 + quad * 4 + r) * Dd + ot * 16 + l16] = (_Float16)acc[ot][r];

    // ---- vt strip: wave's 16 n-rows -> vt[b][d][n], per-wave LDS ----
    const int b  = (int)(row0 >> 11);
    const int nb = (int)(row0 & 2047);            // includes +16w
    _Float16* vdst = vt + (size_t)b * Dd * Nn;
    const int rr = lane >> 2, cg = lane & 3;
    for (int dc = 0; dc < 4; ++dc) {
        #pragma unroll
        for (int c = 0; c < 4; ++c) {
            const f32x4 v = *(const f32x4*)(nodes + (row0 + rr) * Dd + dc * 64 + cg * 16 + 4 * c);
            *(f32x4*)&ts[w][rr][cg * 16 + 4 * c] = v;
        }
        asm volatile("s_waitcnt lgkmcnt(0)" ::: "memory");
        _Float16 tmp[16];
        #pragma unroll
        for (int nn = 0; nn < 16; ++nn) tmp[nn] = (_Float16)ts[w][nn][lane];
        half8 lo, hi;
        #pragma unroll
        for (int e = 0; e < 8; ++e) { lo[e] = tmp[e]; hi[e] = tmp[8 + e]; }
        _Float16* vp = vdst + (size_t)(dc * 64 + lane) * Nn + nb;
        *(half8*)vp = lo;
        *(half8*)(vp + 8) = hi;
        asm volatile("s_waitcnt lgkmcnt(0)" ::: "memory");  // WAR vs next dc
    }
}

// ---------- fused flash-style GAT attention, barrier-free S^T design ----------
// Block = 64 q rows of one batch; 4 independent waves (16 q each). Per m-chunk:
//   S^T = mfma(hm-frag, hq-frag)  -> lane holds 16 m-values of ONE q (q=l16)
//   leaky*adj (adj loaded f32x4 direct, matches fragment layout)
//   online softmax: lane-local + shfl_xor(16,32) over quads
//   P^T f16-packed, quad-redistributed via 16 bpermutes -> PV B-frag
//   PV: wave accumulates its 16 q over ALL 256 d (A-frags from vt, global).
// No __syncthreads anywhere in the main loop; no LDS except epilogue transpose.
__global__ void __launch_bounds__(256, 2)
gat_attn_kernel(const _Float16* __restrict__ h, const _Float16* __restrict__ vt,
                const float* __restrict__ adj, const float* __restrict__ bias,
                float* __restrict__ out) {
    __shared__ float tw[4][16][69];
    const int t = threadIdx.x, w = t >> 6, lane = t & 63;
    const int quad = lane >> 4, l16 = lane & 15;
    const int b  = blockIdx.x & 15;        // batch -> XCD pinning (b%8)
    const int q0 = (blockIdx.x >> 4) * QTI;

    const _Float16* hb = h   + (size_t)b * Nn * Dd;
    const _Float16* vb = vt  + (size_t)b * Dd * Nn;
    const float*   abq = adj + ((size_t)b * Nn + (q0 + 16 * w + l16)) * Nn;  // lane's q row

    // persistent B-frags of QK^T: this wave's q rows (q = q0+16w+l16)
    half8 bq[8];
    {
        const _Float16* s = hb + (size_t)(q0 + 16 * w + l16) * Dd + quad * 8;
        #pragma unroll
        for (int kf = 0; kf < 8; ++kf) bq[kf] = *(const half8*)(s + kf * 32);
    }

    f32x4 ot_[16];   // O^T frags: d = dt*16 + quad*4 + r, q = l16
    #pragma unroll
    for (int dt = 0; dt < 16; ++dt) ot_[dt] = (f32x4){0.f, 0.f, 0.f, 0.f};
    float m_run = -1e30f, l_run = 0.f;

    // bpermute sources for P^T quad-redistribution
    const int s0 = ((lane >> 4) & 1) * 32 + l16;
    const int s1 = s0 + 16;
    const bool qlow = lane < 32;           // Q>>1 == 0

    for (int mb = 0; mb < Nn; mb += MC) {
        // ---- QK^T: S^T strip 64(m) x 16(q); A-frags from global h (L2) ----
        f32x4 st[4];
        #pragma unroll
        for (int mt = 0; mt < 4; ++mt) st[mt] = (f32x4){0.f, 0.f, 0.f, 0.f};
        const _Float16* hm = hb + (size_t)mb * Dd + quad * 8;
        __builtin_amdgcn_s_setprio(1);
        #pragma unroll
        for (int kf = 0; kf < 8; ++kf)
            #pragma unroll
            for (int mt = 0; mt < 4; ++mt) {
                const half8 am = *(const half8*)(hm + (size_t)(mt * 16 + l16) * Dd + kf * 32);
                st[mt] = __builtin_amdgcn_mfma_f32_16x16x32_f16(am, bq[kf], st[mt], 0, 0, 0);
            }
        __builtin_amdgcn_s_setprio(0);

        // ---- leaky * adj + online softmax (lane owns q=l16, 16 m-values) ----
        float rm = -1e30f;
        #pragma unroll
        for (int mt = 0; mt < 4; ++mt) {
            const f32x4 a4 = *(const f32x4*)(abq + mb + mt * 16 + quad * 4);
            #pragma unroll
            for (int r = 0; r < 4; ++r) {
                float s = st[mt][r];
                s = (s >= 0.f) ? s : 0.2f * s;
                s *= a4[r];
                st[mt][r] = s;
                rm = fmaxf(rm, s);
            }
        }
        rm = fmaxf(rm, __shfl_xor(rm, 16));
        rm = fmaxf(rm, __shfl_xor(rm, 32));
        const float mn    = fmaxf(m_run, rm);
        const float alpha = __expf(m_run - mn);
        m_run = mn;
        float rs = 0.f;
        #pragma unroll
        for (int mt = 0; mt < 4; ++mt)
            #pragma unroll
            for (int r = 0; r < 4; ++r) {
                const float p = __expf(st[mt][r] - mn);
                st[mt][r] = p;
                rs += p;
            }
        rs += __shfl_xor(rs, 16);
        rs += __shfl_xor(rs, 32);
        l_run = l_run * alpha + rs;

        #pragma unroll
        for (int dt = 0; dt < 16; ++dt) {
            ot_[dt][0] *= alpha; ot_[dt][1] *= alpha;
            ot_[dt][2] *= alpha; ot_[dt][3] *= alpha;
        }

        // ---- pack P^T (RNE) and redistribute across quads ----
        // source for B[k=32ks+8Q+j][q]: mt'=2ks+(Q>>1), Q'=2(Q&1)+(j>>2), r'=j&3
        uint32_t pk[4][2];
        #pragma unroll
        for (int mt = 0; mt < 4; ++mt) {
            half2v h01, h23;
            h01[0] = (_Float16)st[mt][0]; h01[1] = (_Float16)st[mt][1];
            h23[0] = (_Float16)st[mt][2]; h23[1] = (_Float16)st[mt][3];
            pk[mt][0] = __builtin_bit_cast(uint32_t, h01);
            pk[mt][1] = __builtin_bit_cast(uint32_t, h23);
        }

        // ---- PV: A-frags from vt (global, L2); O^T += V^T . P^T ----
        #pragma unroll
        for (int ks = 0; ks < 2; ++ks) {
            uint4v bw_;
            {
                const int mA = 2 * ks, mB = 2 * ks + 1;
                const uint32_t a00 = (uint32_t)__shfl((int)pk[mA][0], s0);
                const uint32_t b00 = (uint32_t)__shfl((int)pk[mB][0], s0);
                const uint32_t a10 = (uint32_t)__shfl((int)pk[mA][1], s0);
                const uint32_t b10 = (uint32_t)__shfl((int)pk[mB][1], s0);
                const uint32_t a01 = (uint32_t)__shfl((int)pk[mA][0], s1);
                const uint32_t b01 = (uint32_t)__shfl((int)pk[mB][0], s1);
                const uint32_t a11 = (uint32_t)__shfl((int)pk[mA][1], s1);
                const uint32_t b11 = (uint32_t)__shfl((int)pk[mB][1], s1);
                bw_[0] = qlow ? a00 : b00;
                bw_[1] = qlow ? a10 : b10;
                bw_[2] = qlow ? a01 : b01;
                bw_[3] = qlow ? a11 : b11;
            }
            const half8 bp = __builtin_bit_cast(half8, bw_);
            const _Float16* vbase = vb + (size_t)l16 * Nn + mb + ks * 32 + quad * 8;
            __builtin_amdgcn_s_setprio(1);
            #pragma unroll
            for (int dt = 0; dt < 16; ++dt) {
                const half8 va = *(const half8*)(vbase + (size_t)dt * 16 * Nn);
                ot_[dt] = __builtin_amdgcn_mfma_f32_16x16x32_f16(va, bp, ot_[dt], 0, 0, 0);
            }
            __builtin_amdgcn_s_setprio(0);
        }
    }

    // ---- epilogue: scale by 1/L, per-wave LDS transpose, coalesced store ----
    const float invl = 1.f / l_run;
    #pragma unroll
    for (int dt = 0; dt < 16; ++dt) {
        ot_[dt][0] *= invl; ot_[dt][1] *= invl;
        ot_[dt][2] *= invl; ot_[dt][3] *= invl;
    }
    float* T = &tw[w][0][0];
    const int rr = lane >> 2, cg = lane & 3;
    float* orow = out + ((size_t)b * Nn + q0 + 16 * w + rr) * Dd;
    #pragma unroll
    for (int dc = 0; dc < 4; ++dc) {
        #pragma unroll
        for (int k4 = 0; k4 < 4; ++k4) {
            const int dt = dc * 4 + k4;
            #pragma unroll
            for (int r = 0; r < 4; ++r)
                T[l16 * 69 + k4 * 16 + quad * 4 + r] = ot_[dt][r];
        }
        asm volatile("s_waitcnt lgkmcnt(0)" ::: "memory");
        #pragma unroll
        for (int c = 0; c < 4; ++c) {
            f32x4 v;
            #pragma unroll
            for (int e = 0; e < 4; ++e) v[e] = T[rr * 69 + cg * 16 + 4 * c + e];
            const int d = dc * 64 + cg * 16 + 4 * c;
            const f32x4 bs = *(const f32x4*)(bias + d);
            v[0] += bs[0]; v[1] += bs[1]; v[2] += bs[2]; v[3] += bs[3];
            *(f32x4*)(orow + d) = v;
        }
        asm volatile("s_waitcnt lgkmcnt(0)" ::: "memory");  // WAR vs next dc
    }
}

extern "C" void kernel_launch(void* const* d_in, const int* in_sizes, int n_in,
                              void* d_out, int out_size, void* d_ws, size_t ws_size,
                              hipStream_t stream) {
    const float* nodes = (const float*)d_in[0];  // [16,2048,256]
    const float* adj   = (const float*)d_in[1];  // [16,2048,2048]
    const float* W     = (const float*)d_in[2];  // [256,256]
    const float* bias  = (const float*)d_in[3];  // [256]
    float* out = (float*)d_out;

    _Float16* h16 = (_Float16*)d_ws;                       // 16.78 MB
    _Float16* vtp = h16 + (size_t)Bc * Nn * Dd;            // 16.78 MB (total 33.55 MB)

    hipLaunchKernelGGL(wt_transpose_kernel, dim3(4, 4), dim3(256), 0, stream, W);
    hipLaunchKernelGGL(hgemm_vt_kernel, dim3(512), dim3(256), 0, stream, nodes, h16, vtp);
    hipLaunchKernelGGL(gat_attn_kernel, dim3(512), dim3(256), 0, stream, h16, vtp, adj, bias, out);
}

// Round 2
// 566.729 us; speedup vs baseline: 1.5787x; 1.5787x over previous
//
#include <hip/hip_runtime.h>
#include <math.h>
#include <stdint.h>

typedef _Float16 half8 __attribute__((ext_vector_type(8)));
typedef _Float16 half2v __attribute__((ext_vector_type(2)));
typedef float    f32x4 __attribute__((ext_vector_type(4)));
typedef unsigned int uint4v __attribute__((ext_vector_type(4)));

constexpr int Bc = 16, Nn = 2048, Dd = 256;
constexpr int QTI = 64;   // q rows per block (4 waves x 16)
constexpr int MC  = 64;   // m-chunk per iteration

__device__ _Float16 g_Wt[Dd * Dd];   // W^T, f16  (o-major: g_Wt[o][i])

// ---------- transpose W (fp32 [i][o]) -> g_Wt (f16 [o][i]) ----------
__global__ void __launch_bounds__(256)
wt_transpose_kernel(const float* __restrict__ W) {
    __shared__ float ts[64][65];
    const int t = threadIdx.x;
    const int r0 = blockIdx.x * 64;   // i tile
    const int c0 = blockIdx.y * 64;   // o tile
    for (int idx = t; idx < 64 * 64; idx += 256) {
        const int i = idx >> 6, j = idx & 63;
        ts[i][j] = W[(r0 + i) * Dd + c0 + j];
    }
    __syncthreads();
    for (int idx = t; idx < 64 * 64; idx += 256) {
        const int c = idx >> 6, rl = idx & 63;
        g_Wt[(c0 + c) * Dd + r0 + rl] = (_Float16)ts[rl][c];
    }
}

// ---------- transpose nodes (fp32 [b][n][d]) -> vt (f16 [b][d][n]) ----------
// Coalesced both sides (restored: round-1's fused per-wave variant wrote 16B
// into 4KB-strided rows = 4x write amplification).
__global__ void __launch_bounds__(256)
nodes_transpose_kernel(const float* __restrict__ nodes, _Float16* __restrict__ vt) {
    __shared__ float ts[64][65];
    const int t  = threadIdx.x;
    const int n0 = blockIdx.x * 64;
    const int d0 = blockIdx.y * 64;
    const int b  = blockIdx.z;
    const float* src = nodes + (size_t)b * Nn * Dd;
    _Float16*    dst = vt    + (size_t)b * Dd * Nn;
    for (int idx = t; idx < 64 * 64; idx += 256) {
        const int i = idx >> 6, j = idx & 63;
        ts[i][j] = src[(size_t)(n0 + i) * Dd + d0 + j];
    }
    __syncthreads();
    for (int idx = t; idx < 64 * 64; idx += 256) {
        const int d = idx >> 6, nl = idx & 63;
        dst[(size_t)(d0 + d) * Nn + n0 + nl] = (_Float16)ts[nl][d];
    }
}

// ---------- h = nodes @ W (MFMA f16, fp32 accum), W staged in LDS ----------
// 512 blocks x 256 thr; wave owns 16 rows. W^T staged in two 128-o halves
// (padded rows -> uniform bank spread); B-frags come from LDS, not global.
__global__ void __launch_bounds__(256, 2)
hgemm_kernel(const float* __restrict__ nodes, _Float16* __restrict__ h16) {
    __shared__ _Float16 Wt_s[128][264];
    const int t = threadIdx.x, w = t >> 6, lane = t & 63;
    const int quad = lane >> 4, l16 = lane & 15;
    const size_t row0 = (size_t)blockIdx.x * 64 + 16 * w;

    half8 aq[8];
    {
        const float* src = nodes + (row0 + l16) * Dd + quad * 8;
        #pragma unroll
        for (int kf = 0; kf < 8; ++kf) {
            const f32x4 a0 = *(const f32x4*)(src + kf * 32);
            const f32x4 a1 = *(const f32x4*)(src + kf * 32 + 4);
            half8 a;
            a[0] = (_Float16)a0[0]; a[1] = (_Float16)a0[1];
            a[2] = (_Float16)a0[2]; a[3] = (_Float16)a0[3];
            a[4] = (_Float16)a1[0]; a[5] = (_Float16)a1[1];
            a[6] = (_Float16)a1[2]; a[7] = (_Float16)a1[3];
            aq[kf] = a;
        }
    }
    f32x4 acc[16];
    #pragma unroll
    for (int ot = 0; ot < 16; ++ot) acc[ot] = (f32x4){0.f, 0.f, 0.f, 0.f};

    #pragma unroll
    for (int hh = 0; hh < 2; ++hh) {
        if (hh) __syncthreads();   // half-0 reads done before overwrite
        #pragma unroll
        for (int ii = 0; ii < 16; ++ii) {
            const int i = t + ii * 256;
            *(half8*)&Wt_s[i >> 5][(i & 31) * 8] =
                *(const half8*)&g_Wt[(size_t)(hh * 128 + (i >> 5)) * Dd + (i & 31) * 8];
        }
        __syncthreads();
        #pragma unroll
        for (int kf = 0; kf < 8; ++kf)
            #pragma unroll
            for (int ot = 0; ot < 8; ++ot) {
                const half8 bw = *(const half8*)&Wt_s[ot * 16 + l16][kf * 32 + quad * 8];
                acc[hh * 8 + ot] = __builtin_amdgcn_mfma_f32_16x16x32_f16(aq[kf], bw, acc[hh * 8 + ot], 0, 0, 0);
            }
    }
    #pragma unroll
    for (int idx = 0; idx < 16; ++idx) {
        const int hh = idx >> 3, ot = idx & 7;
        #pragma unroll
        for (int r = 0; r < 4; ++r)
            h16[(row0 + quad * 4 + r) * Dd + hh * 128 + ot * 16 + l16] = (_Float16)acc[idx][r];
    }
}

// ---------- fused flash-style GAT attention (S^T design, pipelined LDS) ----------
// Block = 64 q rows of one batch; 4 waves (16 q each), P stays in-wave.
// Per m-chunk: QK^T from LDS hm_s; leaky*adj (adj in regs, prefetched one
// chunk ahead); online softmax lane-local + 2 shfl; P^T packed f16 and
// quad-redistributed via bpermute; PV from LDS V_s (full 256 d per wave).
// Staging: global->reg issued ONE CHUNK AHEAD, reg->ds_write between two raw
// s_barriers (lgkmcnt(0) only -- global loads never drained in the loop).
__global__ void __launch_bounds__(256, 2)
gat_attn_kernel(const _Float16* __restrict__ h, const _Float16* __restrict__ vt,
                const float* __restrict__ adj, const float* __restrict__ bias,
                float* __restrict__ out) {
    __shared__ __align__(16) char lds_raw[70656];
    _Float16 (*hm_s)[264] = (_Float16 (*)[264])lds_raw;                 // 64 x 264  (33792 B)
    _Float16 (*V_s)[72]   = (_Float16 (*)[72])(lds_raw + 33792);        // 256 x 72  (36864 B)
    float (*tw)[16][69]   = (float (*)[16][69])lds_raw;                 // epilogue alias

    const int t = threadIdx.x, w = t >> 6, lane = t & 63;
    const int quad = lane >> 4, l16 = lane & 15;
    const int b  = blockIdx.x & 15;        // batch -> XCD affinity
    const int q0 = (blockIdx.x >> 4) * QTI;

    const _Float16* hb = h   + (size_t)b * Nn * Dd;
    const _Float16* vb = vt  + (size_t)b * Dd * Nn;
    const float*   abq = adj + ((size_t)b * Nn + (q0 + 16 * w + l16)) * Nn;  // lane's q row

    // ---- issue chunk-0 staging loads (hm + V + adj) ----
    half8 hmr[8], vr[8];
    #pragma unroll
    for (int ii = 0; ii < 8; ++ii) {
        const int i = t + ii * 256;
        hmr[ii] = *(const half8*)(hb + (size_t)(i >> 5) * Dd + (i & 31) * 8);
        vr[ii]  = *(const half8*)(vb + (size_t)(i >> 3) * Nn + (i & 7) * 8);
    }
    f32x4 adjr[4];
    #pragma unroll
    for (int mt = 0; mt < 4; ++mt)
        adjr[mt] = *(const f32x4*)(abq + mt * 16 + quad * 4);

    // persistent B-frags of QK^T: this wave's q rows (q = q0+16w+l16)
    half8 bq[8];
    {
        const _Float16* s = hb + (size_t)(q0 + 16 * w + l16) * Dd + quad * 8;
        #pragma unroll
        for (int kf = 0; kf < 8; ++kf) bq[kf] = *(const half8*)(s + kf * 32);
    }

    f32x4 ot_[16];   // O^T frags: d = dt*16 + quad*4 + r, q = l16
    #pragma unroll
    for (int dt = 0; dt < 16; ++dt) ot_[dt] = (f32x4){0.f, 0.f, 0.f, 0.f};
    float m_run = -1e30f, l_run = 0.f;

    const int s0 = ((lane >> 4) & 1) * 32 + l16;
    const int s1 = s0 + 16;
    const bool qlow = lane < 32;

    // ---- write chunk 0 to LDS (auto vmcnt wait on hmr/vr); issue chunk 1 ----
    #pragma unroll
    for (int ii = 0; ii < 8; ++ii) {
        const int i = t + ii * 256;
        *(half8*)&hm_s[i >> 5][(i & 31) * 8] = hmr[ii];
        *(half8*)&V_s[i >> 3][(i & 7) * 8]   = vr[ii];
    }
    #pragma unroll
    for (int ii = 0; ii < 8; ++ii) {
        const int i = t + ii * 256;
        hmr[ii] = *(const half8*)(hb + (size_t)(MC + (i >> 5)) * Dd + (i & 31) * 8);
        vr[ii]  = *(const half8*)(vb + (size_t)(i >> 3) * Nn + MC + (i & 7) * 8);
    }
    asm volatile("s_waitcnt lgkmcnt(0)" ::: "memory");
    __builtin_amdgcn_s_barrier();
    asm volatile("" ::: "memory");

    for (int mb = 0; mb < Nn; mb += MC) {
        // ---- QK^T: S^T strip 64(m) x 16(q), A-frags from LDS ----
        f32x4 st[4];
        #pragma unroll
        for (int mt = 0; mt < 4; ++mt) st[mt] = (f32x4){0.f, 0.f, 0.f, 0.f};
        __builtin_amdgcn_s_setprio(1);
        #pragma unroll
        for (int kf = 0; kf < 8; ++kf)
            #pragma unroll
            for (int mt = 0; mt < 4; ++mt) {
                const half8 am = *(const half8*)&hm_s[mt * 16 + l16][kf * 32 + quad * 8];
                st[mt] = __builtin_amdgcn_mfma_f32_16x16x32_f16(am, bq[kf], st[mt], 0, 0, 0);
            }
        __builtin_amdgcn_s_setprio(0);

        // ---- leaky * adj + online softmax (lane owns q=l16, 16 m-values) ----
        float rm = -1e30f;
        #pragma unroll
        for (int mt = 0; mt < 4; ++mt) {
            const f32x4 a4 = adjr[mt];
            #pragma unroll
            for (int r = 0; r < 4; ++r) {
                float s = st[mt][r];
                s = (s >= 0.f) ? s : 0.2f * s;
                s *= a4[r];
                st[mt][r] = s;
                rm = fmaxf(rm, s);
            }
        }
        // prefetch next chunk's adj right after last use (hidden under PV)
        if (mb + MC < Nn) {
            #pragma unroll
            for (int mt = 0; mt < 4; ++mt)
                adjr[mt] = *(const f32x4*)(abq + mb + MC + mt * 16 + quad * 4);
        }
        rm = fmaxf(rm, __shfl_xor(rm, 16));
        rm = fmaxf(rm, __shfl_xor(rm, 32));
        const float mn    = fmaxf(m_run, rm);
        const float alpha = __expf(m_run - mn);
        m_run = mn;
        float rs = 0.f;
        #pragma unroll
        for (int mt = 0; mt < 4; ++mt)
            #pragma unroll
            for (int r = 0; r < 4; ++r) {
                const float p = __expf(st[mt][r] - mn);
                st[mt][r] = p;
                rs += p;
            }
        rs += __shfl_xor(rs, 16);
        rs += __shfl_xor(rs, 32);
        l_run = l_run * alpha + rs;

        #pragma unroll
        for (int dt = 0; dt < 16; ++dt) {
            ot_[dt][0] *= alpha; ot_[dt][1] *= alpha;
            ot_[dt][2] *= alpha; ot_[dt][3] *= alpha;
        }

        // ---- pack P^T (RNE) and redistribute across quads ----
        uint32_t pk[4][2];
        #pragma unroll
        for (int mt = 0; mt < 4; ++mt) {
            half2v h01, h23;
            h01[0] = (_Float16)st[mt][0]; h01[1] = (_Float16)st[mt][1];
            h23[0] = (_Float16)st[mt][2]; h23[1] = (_Float16)st[mt][3];
            pk[mt][0] = __builtin_bit_cast(uint32_t, h01);
            pk[mt][1] = __builtin_bit_cast(uint32_t, h23);
        }

        // ---- PV: A-frags from LDS V_s; O^T += V^T . P^T ----
        #pragma unroll
        for (int ks = 0; ks < 2; ++ks) {
            uint4v bw_;
            {
                const int mA = 2 * ks, mB = 2 * ks + 1;
                const uint32_t a00 = (uint32_t)__shfl((int)pk[mA][0], s0);
                const uint32_t b00 = (uint32_t)__shfl((int)pk[mB][0], s0);
                const uint32_t a10 = (uint32_t)__shfl((int)pk[mA][1], s0);
                const uint32_t b10 = (uint32_t)__shfl((int)pk[mB][1], s0);
                const uint32_t a01 = (uint32_t)__shfl((int)pk[mA][0], s1);
                const uint32_t b01 = (uint32_t)__shfl((int)pk[mB][0], s1);
                const uint32_t a11 = (uint32_t)__shfl((int)pk[mA][1], s1);
                const uint32_t b11 = (uint32_t)__shfl((int)pk[mB][1], s1);
                bw_[0] = qlow ? a00 : b00;
                bw_[1] = qlow ? a10 : b10;
                bw_[2] = qlow ? a01 : b01;
                bw_[3] = qlow ? a11 : b11;
            }
            const half8 bp = __builtin_bit_cast(half8, bw_);
            __builtin_amdgcn_s_setprio(1);
            #pragma unroll
            for (int dt = 0; dt < 16; ++dt) {
                const half8 va = *(const half8*)&V_s[dt * 16 + l16][ks * 32 + quad * 8];
                ot_[dt] = __builtin_amdgcn_mfma_f32_16x16x32_f16(va, bp, ot_[dt], 0, 0, 0);
            }
            __builtin_amdgcn_s_setprio(0);
        }

        // ---- restage: write chunk mb+1 (regs already in flight), issue mb+2 ----
        if (mb + MC < Nn) {
            asm volatile("" ::: "memory");
            __builtin_amdgcn_s_barrier();          // all waves done reading chunk mb
            asm volatile("" ::: "memory");
            #pragma unroll
            for (int ii = 0; ii < 8; ++ii) {
                const int i = t + ii * 256;
                *(half8*)&hm_s[i >> 5][(i & 31) * 8] = hmr[ii];   // auto vmcnt wait (~0: issued a chunk ago)
                *(half8*)&V_s[i >> 3][(i & 7) * 8]   = vr[ii];
            }
            if (mb + 2 * MC < Nn) {
                #pragma unroll
                for (int ii = 0; ii < 8; ++ii) {
                    const int i = t + ii * 256;
                    hmr[ii] = *(const half8*)(hb + (size_t)(mb + 2 * MC + (i >> 5)) * Dd + (i & 31) * 8);
                    vr[ii]  = *(const half8*)(vb + (size_t)(i >> 3) * Nn + mb + 2 * MC + (i & 7) * 8);
                }
            }
            asm volatile("s_waitcnt lgkmcnt(0)" ::: "memory");
            __builtin_amdgcn_s_barrier();          // chunk mb+1 visible
            asm volatile("" ::: "memory");
        }
    }

    // ---- epilogue: scale by 1/L, per-wave LDS transpose, coalesced store ----
    __syncthreads();                               // before aliasing tw over hm_s
    const float invl = 1.f / l_run;
    #pragma unroll
    for (int dt = 0; dt < 16; ++dt) {
        ot_[dt][0] *= invl; ot_[dt][1] *= invl;
        ot_[dt][2] *= invl; ot_[dt][3] *= invl;
    }
    float* T = &tw[w][0][0];
    const int rr = lane >> 2, cg = lane & 3;
    float* orow = out + ((size_t)b * Nn + q0 + 16 * w + rr) * Dd;
    #pragma unroll
    for (int dc = 0; dc < 4; ++dc) {
        #pragma unroll
        for (int k4 = 0; k4 < 4; ++k4) {
            const int dt = dc * 4 + k4;
            #pragma unroll
            for (int r = 0; r < 4; ++r)
                T[l16 * 69 + k4 * 16 + quad * 4 + r] = ot_[dt][r];
        }
        asm volatile("s_waitcnt lgkmcnt(0)" ::: "memory");
        #pragma unroll
        for (int c = 0; c < 4; ++c) {
            f32x4 v;
            #pragma unroll
            for (int e = 0; e < 4; ++e) v[e] = T[rr * 69 + cg * 16 + 4 * c + e];
            const int d = dc * 64 + cg * 16 + 4 * c;
            const f32x4 bs = *(const f32x4*)(bias + d);
            v[0] += bs[0]; v[1] += bs[1]; v[2] += bs[2]; v[3] += bs[3];
            *(f32x4*)(orow + d) = v;
        }
        asm volatile("s_waitcnt lgkmcnt(0)" ::: "memory");  // WAR vs next dc
    }
}

extern "C" void kernel_launch(void* const* d_in, const int* in_sizes, int n_in,
                              void* d_out, int out_size, void* d_ws, size_t ws_size,
                              hipStream_t stream) {
    const float* nodes = (const float*)d_in[0];  // [16,2048,256]
    const float* adj   = (const float*)d_in[1];  // [16,2048,2048]
    const float* W     = (const float*)d_in[2];  // [256,256]
    const float* bias  = (const float*)d_in[3];  // [256]
    float* out = (float*)d_out;

    _Float16* h16 = (_Float16*)d_ws;                       // 16.78 MB
    _Float16* vtp = h16 + (size_t)Bc * Nn * Dd;            // 16.78 MB (total 33.55 MB)

    hipLaunchKernelGGL(wt_transpose_kernel, dim3(4, 4), dim3(256), 0, stream, W);
    hipLaunchKernelGGL(nodes_transpose_kernel, dim3(32, 4, 16), dim3(256), 0, stream, nodes, vtp);
    hipLaunchKernelGGL(hgemm_kernel, dim3(512), dim3(256), 0, stream, nodes, h16);
    hipLaunchKernelGGL(gat_attn_kernel, dim3(512), dim3(256), 0, stream, h16, vtp, adj, bias, out);
}